// Round 6
// baseline (357.794 us; speedup 1.0000x reference)
//
#include <hip/hip_runtime.h>
#include <hip/hip_fp16.h>

#define NN 100000
#define NE 1600000
#define D 128
#define NC 8
#define NBUCK 391   // ceil(NN / 256) buckets of 256 node-ids
#define CHUNK 4096  // edges per binning block

typedef _Float16 half8 __attribute__((ext_vector_type(8)));
typedef float f32x4 __attribute__((ext_vector_type(4)));

// ---------------- utility ----------------
__global__ void k_zero(int* __restrict__ p, int n) {
    int i = blockIdx.x * blockDim.x + threadIdx.x;
    if (i < n) p[i] = 0;
}

// ---------------- pass 0: global bucket histogram ----------------
__global__ __launch_bounds__(256) void k_bhist(const int* __restrict__ dst,
                                               int* __restrict__ gcount, int E) {
    __shared__ int h[NBUCK];
    for (int i = threadIdx.x; i < NBUCK; i += 256) h[i] = 0;
    __syncthreads();
    const int base0 = blockIdx.x * CHUNK;
#pragma unroll
    for (int i = 0; i < 4; ++i) {
        int e = base0 + i * 1024 + threadIdx.x * 4;
        if (e < E) {  // E % 4 == 0 -> full int4 safe
            int4 d4 = *(const int4*)&dst[e];
            atomicAdd(&h[d4.x >> 8], 1);
            atomicAdd(&h[d4.y >> 8], 1);
            atomicAdd(&h[d4.z >> 8], 1);
            atomicAdd(&h[d4.w >> 8], 1);
        }
    }
    __syncthreads();
    for (int i = threadIdx.x; i < NBUCK; i += 256) {
        int c = h[i];
        if (c) atomicAdd(&gcount[i], c);
    }
}

// ---------------- bucket scan (1 block, 512 threads) ----------------
__global__ void k_bscan(const int* __restrict__ gcount, int* __restrict__ bstart,
                        int* __restrict__ bcursor) {
    __shared__ int sd[512];
    int t = threadIdx.x;
    int v = (t < NBUCK) ? gcount[t] : 0;
    sd[t] = v;
    __syncthreads();
    for (int off = 1; off < 512; off <<= 1) {
        int y = (t >= off) ? sd[t - off] : 0;
        __syncthreads();
        sd[t] += y;
        __syncthreads();
    }
    int ex = sd[t] - v;  // exclusive prefix
    if (t <= NBUCK) bstart[t] = ex;   // bstart[NBUCK] == E
    if (t < NBUCK) bcursor[t] = ex;
}

// ---------------- pass 1: scatter edges into bucket-major staging ----------------
__global__ __launch_bounds__(256) void k_bscatter(const int* __restrict__ src,
                                                  const int* __restrict__ dst,
                                                  int* __restrict__ bcursor,
                                                  int2* __restrict__ staged, int E) {
    __shared__ int h[NBUCK];
    __shared__ int cur[NBUCK];
    const int t = threadIdx.x;
    for (int i = t; i < NBUCK; i += 256) h[i] = 0;
    __syncthreads();
    const int base0 = blockIdx.x * CHUNK;
    int4 d4[4], s4[4];
    bool val[4];
#pragma unroll
    for (int i = 0; i < 4; ++i) {
        int e = base0 + i * 1024 + t * 4;
        val[i] = e < E;
        if (val[i]) {
            d4[i] = *(const int4*)&dst[e];
            s4[i] = *(const int4*)&src[e];
            atomicAdd(&h[d4[i].x >> 8], 1);
            atomicAdd(&h[d4[i].y >> 8], 1);
            atomicAdd(&h[d4[i].z >> 8], 1);
            atomicAdd(&h[d4[i].w >> 8], 1);
        }
    }
    __syncthreads();
    // reserve a contiguous range per bucket for this block
    for (int i = t; i < NBUCK; i += 256) {
        int c = h[i];
        cur[i] = c ? atomicAdd(&bcursor[i], c) : 0;
    }
    __syncthreads();
#pragma unroll
    for (int i = 0; i < 4; ++i) {
        if (val[i]) {
            int p;
            p = atomicAdd(&cur[d4[i].x >> 8], 1); staged[p] = make_int2(s4[i].x, d4[i].x);
            p = atomicAdd(&cur[d4[i].y >> 8], 1); staged[p] = make_int2(s4[i].y, d4[i].y);
            p = atomicAdd(&cur[d4[i].z >> 8], 1); staged[p] = make_int2(s4[i].z, d4[i].z);
            p = atomicAdd(&cur[d4[i].w >> 8], 1); staged[p] = make_int2(s4[i].w, d4[i].w);
        }
    }
}

// ---------------- pass 2: per-bucket local CSR build (one block per bucket) ------
__global__ __launch_bounds__(256) void k_bfill(const int2* __restrict__ staged,
                                               const int* __restrict__ bstart,
                                               int* __restrict__ rowstart,
                                               int* __restrict__ cnt,
                                               float* __restrict__ dinv,
                                               int* __restrict__ csr) {
    const int b = blockIdx.x;
    const int t = threadIdx.x;
    const int bs = bstart[b], be = bstart[b + 1];
    __shared__ int lc[256];  // per-node count, later reused as cursor
    __shared__ int ls[256];  // per-node global csr start
    __shared__ int sd[256];  // scan temp
    lc[t] = 0;
    __syncthreads();
    for (int i = bs + t; i < be; i += 256) {
        int2 e = staged[i];
        atomicAdd(&lc[e.y & 255], 1);
    }
    __syncthreads();
    int v = lc[t];
    sd[t] = v;
    __syncthreads();
    for (int off = 1; off < 256; off <<= 1) {
        int y = (t >= off) ? sd[t - off] : 0;
        __syncthreads();
        sd[t] += y;
        __syncthreads();
    }
    int ex = sd[t] - v;
    ls[t] = bs + ex;
    int node = (b << 8) + t;
    if (node < NN) {
        rowstart[node] = bs + ex;
        cnt[node] = v;
        dinv[node] = rsqrtf((float)(v + 1));  // +1 = self-loop
    }
    lc[t] = 0;  // reuse as cursor
    __syncthreads();
    for (int i = bs + t; i < be; i += 256) {
        int2 e = staged[i];
        int li = e.y & 255;
        int p = atomicAdd(&lc[li], 1);
        csr[ls[li] + p] = e.x;
    }
}

// ---------------- W convert+transpose: wt[col][k] = half(W[k][col]) ----------------
__global__ void k_cvtw(const float* __restrict__ W, __half* __restrict__ wt) {
    int t = threadIdx.x;
    for (int i = t; i < D * D; i += 256) {
        int k = i >> 7, c = i & 127;
        wt[c * D + k] = __float2half(W[i]);
    }
}

// ---------------- MFMA GEMM: hout[r] = half( (A[r] @ W) * dinv[r] ) ----------------
// 4 waves/block; wave = 16 rows x 64 cols (4 col-tiles x 4 K-steps of 16x16x32).
template <bool F32IN>
__global__ __launch_bounds__(256) void k_mgemm(const void* __restrict__ Ain,
                                               const __half* __restrict__ wt,
                                               const float* __restrict__ dinv,
                                               __half* __restrict__ hout) {
    const int tid = threadIdx.x;
    const int lane = tid & 63;
    const int wave = tid >> 6;
    const int wr = wave >> 1, wc = wave & 1;
    const int row0 = blockIdx.x * 32 + wr * 16;
    const int arow = row0 + (lane & 15);
    const int kg = lane >> 4;

    half8 afrag[4];
    if constexpr (F32IN) {
        const float* A = (const float*)Ain;
#pragma unroll
        for (int s = 0; s < 4; ++s) {
            const float* p = &A[(size_t)arow * D + s * 32 + kg * 8];
            float4 f0 = *(const float4*)p;
            float4 f1 = *(const float4*)(p + 4);
            half8 a;
            a[0] = (_Float16)f0.x; a[1] = (_Float16)f0.y;
            a[2] = (_Float16)f0.z; a[3] = (_Float16)f0.w;
            a[4] = (_Float16)f1.x; a[5] = (_Float16)f1.y;
            a[6] = (_Float16)f1.z; a[7] = (_Float16)f1.w;
            afrag[s] = a;
        }
    } else {
        const __half* A = (const __half*)Ain;
#pragma unroll
        for (int s = 0; s < 4; ++s)
            afrag[s] = *(const half8*)&A[(size_t)arow * D + s * 32 + kg * 8];
    }

    f32x4 acc[4] = {};
    const int colbase = wc * 64;
#pragma unroll
    for (int c = 0; c < 4; ++c) {
        const int col = colbase + c * 16 + (lane & 15);
#pragma unroll
        for (int s = 0; s < 4; ++s) {
            half8 b = *(const half8*)&wt[col * D + s * 32 + kg * 8];
            acc[c] = __builtin_amdgcn_mfma_f32_16x16x32_f16(afrag[s], b, acc[c], 0, 0, 0);
        }
    }

#pragma unroll
    for (int r = 0; r < 4; ++r) {
        const int row = row0 + kg * 4 + r;
        const float dv = dinv[row];
#pragma unroll
        for (int c = 0; c < 4; ++c) {
            const int col = colbase + c * 16 + (lane & 15);
            hout[(size_t)row * D + col] = __float2half(acc[c][r] * dv);
        }
    }
}

__device__ inline void add8h(float* acc, float4 raw) {
    const __half2* hp = (const __half2*)&raw;
#pragma unroll
    for (int q = 0; q < 4; ++q) {
        float2 f = __half22float2(hp[q]);
        acc[2 * q] += f.x;
        acc[2 * q + 1] += f.y;
    }
}

// ---------------- aggregation v4: prefetch-then-accumulate gather ----------------
// One wave per node; 4 groups x 16 lanes; each group prefetches up to 8 neighbor
// rows (guarded independent loads) before any dependent add -> up to 32 rows in
// flight per wave at ANY degree (covers deg<=32 in one pass; Poisson(16) tail loops).
// MODE 0: out = fp16 relu row (hout).  MODE 1: fused classifier head ->
//   softmax(relu_row @ Wout + bout) written to fout (fp32 [node][8]).
template <int MODE>
__global__ __launch_bounds__(256) void k_agg(const __half* __restrict__ hs,
                                             const int* __restrict__ rowstart,
                                             const int* __restrict__ cnt,
                                             const int* __restrict__ csr_src,
                                             const float* __restrict__ dinv,
                                             const float* __restrict__ bias,
                                             __half* __restrict__ hout,
                                             float* __restrict__ fout,
                                             const float* __restrict__ Wout,
                                             const float* __restrict__ bout) {
    __shared__ float ws[MODE == 1 ? D * NC : 1];
    if constexpr (MODE == 1) {
        for (int i = threadIdx.x; i < D * NC; i += 256) ws[i] = Wout[i];
        __syncthreads();
    }
    const int node = blockIdx.x * 4 + (threadIdx.x >> 6);  // NN % 4 == 0, exact grid
    const int lane = threadIdx.x & 63;
    const int g = lane >> 4;           // neighbor group 0..3
    const int f8 = (lane & 15) << 3;   // feature offset (8 halves = 16B per lane)

    float acc[8] = {};
    if (g == 0) add8h(acc, *(const float4*)&hs[(size_t)node * D + f8]);  // self-loop

    const int c = cnt[node];
    const int* __restrict__ cl = csr_src + rowstart[node];

    // group g owns neighbors g, g+4, g+8, ...; prefetch 8 per pass
    int t = g;
    while (t < c) {
        float4 v[8];
#pragma unroll
        for (int i = 0; i < 8; ++i) {
            int tt = t + 4 * i;
            if (tt < c) {
                int s = cl[tt];
                v[i] = *(const float4*)&hs[(size_t)s * D + f8];
            }
        }
#pragma unroll
        for (int i = 0; i < 8; ++i) {
            int tt = t + 4 * i;
            if (tt < c) add8h(acc, v[i]);
        }
        t += 32;
    }

    // combine the 4 groups
#pragma unroll
    for (int q = 0; q < 8; ++q) {
        acc[q] += __shfl_xor(acc[q], 16);
        acc[q] += __shfl_xor(acc[q], 32);
    }

    if (g == 0) {
        const float dv = dinv[node];
        float r[8];
#pragma unroll
        for (int q = 0; q < 8; ++q) r[q] = fmaxf(fmaf(dv, acc[q], bias[f8 + q]), 0.f);

        if constexpr (MODE == 0) {
            union { float4 f; __half2 h[4]; } u;
#pragma unroll
            for (int q = 0; q < 4; ++q) u.h[q] = __floats2half2_rn(r[2 * q], r[2 * q + 1]);
            *(float4*)&hout[(size_t)node * D + f8] = u.f;
        } else {
            // per-lane partial logits over this lane's 8 features
            float lg[NC] = {};
#pragma unroll
            for (int q = 0; q < 8; ++q) {
                const float* wrow = &ws[(f8 + q) * NC];
#pragma unroll
                for (int c8 = 0; c8 < NC; ++c8) lg[c8] = fmaf(r[q], wrow[c8], lg[c8]);
            }
            // reduce across the 16 lanes of group 0 (stays within lanes 0..15)
#pragma unroll
            for (int off = 1; off < 16; off <<= 1)
#pragma unroll
                for (int c8 = 0; c8 < NC; ++c8) lg[c8] += __shfl_xor(lg[c8], off);
            // softmax (redundant on all 16 lanes; lane 0 writes)
            float m = -1e30f;
#pragma unroll
            for (int c8 = 0; c8 < NC; ++c8) { lg[c8] += bout[c8]; m = fmaxf(m, lg[c8]); }
            float ssum = 0.f;
#pragma unroll
            for (int c8 = 0; c8 < NC; ++c8) { lg[c8] = __expf(lg[c8] - m); ssum += lg[c8]; }
            float inv = 1.0f / ssum;
            if ((lane & 15) == 0) {
                float4 o0 = make_float4(lg[0] * inv, lg[1] * inv, lg[2] * inv, lg[3] * inv);
                float4 o1 = make_float4(lg[4] * inv, lg[5] * inv, lg[6] * inv, lg[7] * inv);
                *(float4*)&fout[(size_t)node * NC] = o0;
                *(float4*)&fout[(size_t)node * NC + 4] = o1;
            }
        }
    }
}

// ---------------- launch ----------------
extern "C" void kernel_launch(void* const* d_in, const int* in_sizes, int n_in,
                              void* d_out, int out_size, void* d_ws, size_t ws_size,
                              hipStream_t stream) {
    const float* x    = (const float*)d_in[0];
    const int*   ei   = (const int*)d_in[1];   // [2][NE]: row 0 = src, row 1 = dst
    const float* W1   = (const float*)d_in[2];
    const float* b1   = (const float*)d_in[3];
    const float* W2   = (const float*)d_in[4];
    const float* b2   = (const float*)d_in[5];
    const float* Wout = (const float*)d_in[6];
    const float* bout = (const float*)d_in[7];
    float* out = (float*)d_out;

    size_t off = 0;
    char* base = (char*)d_ws;
    auto alloc = [&](size_t bytes) -> void* {
        void* p = base + off;
        off += (bytes + 255) & ~(size_t)255;
        return p;
    };
    int*    cnt      = (int*)alloc((size_t)NN * 4);
    int*    rowstart = (int*)alloc((size_t)NN * 4);
    int*    gcount   = (int*)alloc((size_t)(NBUCK + 1) * 4);
    int*    bstart   = (int*)alloc((size_t)(NBUCK + 1) * 4);
    int*    bcursor  = (int*)alloc((size_t)(NBUCK + 1) * 4);
    int*    csr      = (int*)alloc((size_t)NE * 4);
    float*  dinv     = (float*)alloc((size_t)NN * 4);
    __half* wt1      = (__half*)alloc((size_t)D * D * 2);
    __half* wt2      = (__half*)alloc((size_t)D * D * 2);
    __half* h16a     = (__half*)alloc((size_t)NN * D * 2);
    __half* h16f     = (__half*)alloc((size_t)NN * D * 2);
    int2*   staged   = (int2*)h16f;  // alias: consumed by k_bfill before h16f is written
    if (off > ws_size) return;  // workspace too small; fail visibly

    const int* src = ei;
    const int* dst = ei + NE;

    // ---- CSR build via bucketed counting sort ----
    int bin_grid = (NE + CHUNK - 1) / CHUNK;  // 391
    k_zero<<<2, 256, 0, stream>>>(gcount, NBUCK);
    k_bhist<<<bin_grid, 256, 0, stream>>>(dst, gcount, NE);
    k_bscan<<<1, 512, 0, stream>>>(gcount, bstart, bcursor);
    k_bscatter<<<bin_grid, 256, 0, stream>>>(src, dst, bcursor, staged, NE);
    k_bfill<<<NBUCK, 256, 0, stream>>>(staged, bstart, rowstart, cnt, dinv, csr);

    // ---- weight prep ----
    k_cvtw<<<1, 256, 0, stream>>>(W1, wt1);
    k_cvtw<<<1, 256, 0, stream>>>(W2, wt2);

    int gemm_grid = NN / 32;       // 3125 exactly
    int agg_grid = NN / 4;         // 25000 exactly
    // layer 1
    k_mgemm<true><<<gemm_grid, 256, 0, stream>>>(x, wt1, dinv, h16a);
    k_agg<0><<<agg_grid, 256, 0, stream>>>(h16a, rowstart, cnt, csr, dinv, b1,
                                           h16f, nullptr, nullptr, nullptr);
    // layer 2
    k_mgemm<false><<<gemm_grid, 256, 0, stream>>>(h16f, wt2, dinv, h16a);
    // layer-2 aggregation with fused classifier head + softmax -> d_out
    k_agg<1><<<agg_grid, 256, 0, stream>>>(h16a, rowstart, cnt, csr, dinv, b2,
                                           nullptr, out, Wout, bout);
}